// Round 1
// baseline (1627.678 us; speedup 1.0000x reference)
//
#include <hip/hip_runtime.h>

static constexpr int kN = 100000;
static constexpr int kE = 1600000;
static constexpr float kEps = 1e-5f;

// ---------------------------------------------------------------- CSR build
__global__ void count_deg_k(const int* __restrict__ dst, int* __restrict__ deg) {
  int e = blockIdx.x * blockDim.x + threadIdx.x;
  if (e < kE) atomicAdd(&deg[dst[e]], 1);
}

__global__ void dinv_k(const int* __restrict__ deg, float* __restrict__ dinv) {
  int i = blockIdx.x * blockDim.x + threadIdx.x;
  if (i < kN) dinv[i] = rsqrtf((float)(deg[i] + 1));  // +1 self-loop, deg>=1
}

// Bump-allocate CSR row starts: wave-level scan + 1 atomic per wave.
__global__ void alloc_rows_k(const int* __restrict__ deg, int* __restrict__ row_start,
                             int* __restrict__ cursor, int* __restrict__ counter) {
  int i = blockIdx.x * blockDim.x + threadIdx.x;
  int lane = threadIdx.x & 63;
  int d = (i < kN) ? deg[i] : 0;
  int x = d;  // inclusive scan over wave
  #pragma unroll
  for (int off = 1; off < 64; off <<= 1) {
    int y = __shfl_up(x, off, 64);
    if (lane >= off) x += y;
  }
  int total = __shfl(x, 63, 64);
  int base = 0;
  if (lane == 63) base = atomicAdd(counter, total);
  base = __shfl(base, 63, 64);
  int start = base + x - d;  // exclusive prefix
  if (i < kN) { row_start[i] = start; cursor[i] = start; }
}

__global__ void scatter_k(const int* __restrict__ src, const int* __restrict__ dst,
                          const float* __restrict__ dinv, int* __restrict__ cursor,
                          int* __restrict__ csr_src, float* __restrict__ csr_w) {
  int e = blockIdx.x * blockDim.x + threadIdx.x;
  if (e >= kE) return;
  int s = src[e], d = dst[e];
  int pos = atomicAdd(&cursor[d], 1);
  csr_src[pos] = s;
  csr_w[pos] = dinv[s] * dinv[d];
}

// ---------------------------------------------------------------- GEMM (fp32, vector ALU)
// C[nrows x BN] = (RELU?relu(A):A)[nrows x 128] @ W[128 x BN]
template <int BN, bool RELU>
__global__ void gemm_k(const float* __restrict__ A, const float* __restrict__ W,
                       float* __restrict__ C, int nrows) {
  constexpr int BM = 128, BK = 8, TM = 8, TN = 8;
  constexpr int TX = BN / TN;      // 16 or 8
  constexpr int NT = TX * (BM / TM);
  __shared__ float As[BK][BM];
  __shared__ float Ws[BK][BN];
  int tid = threadIdx.x;
  int row0 = blockIdx.x * BM;
  int ty = tid / TX, tx = tid % TX;
  float acc[TM][TN] = {};
  for (int k0 = 0; k0 < 128; k0 += BK) {
    for (int i = tid; i < BM * BK; i += NT) {
      int r = i / BK, kk = i % BK;
      int gr = row0 + r;
      float v = (gr < nrows) ? A[gr * 128 + k0 + kk] : 0.f;
      if (RELU) v = fmaxf(v, 0.f);
      As[kk][r] = v;
    }
    for (int i = tid; i < BK * BN; i += NT) {
      int kk = i / BN, c = i % BN;
      Ws[kk][c] = W[(k0 + kk) * BN + c];
    }
    __syncthreads();
    #pragma unroll
    for (int kk = 0; kk < BK; ++kk) {
      float a[TM], b[TN];
      #pragma unroll
      for (int m = 0; m < TM; ++m) a[m] = As[kk][ty * TM + m];
      #pragma unroll
      for (int n = 0; n < TN; ++n) b[n] = Ws[kk][tx * TN + n];
      #pragma unroll
      for (int m = 0; m < TM; ++m)
        #pragma unroll
        for (int n = 0; n < TN; ++n)
          acc[m][n] += a[m] * b[n];
    }
    __syncthreads();
  }
  for (int m = 0; m < TM; ++m) {
    int gr = row0 + ty * TM + m;
    if (gr >= nrows) continue;
    #pragma unroll
    for (int n = 0; n < TN; ++n)
      C[gr * BN + tx * TN + n] = acc[m][n];
  }
}

// ---------------------------------------------------------------- aggregation (gather, 1 wave/node)
template <int F>
__global__ void aggregate_k(const float* __restrict__ H,
                            const int* __restrict__ row_start,
                            const int* __restrict__ deg,
                            const int* __restrict__ csr_src,
                            const float* __restrict__ csr_w,
                            const float* __restrict__ dinv,
                            const float* __restrict__ bias,
                            float* __restrict__ outp) {
  int wave = (int)((blockIdx.x * blockDim.x + threadIdx.x) >> 6);
  if (wave >= kN) return;
  int lane = threadIdx.x & 63;
  int rs = row_start[wave];
  int dg = deg[wave];
  float di = dinv[wave];
  if constexpr (F == 128) {
    const float2* H2 = (const float2*)H;
    float2 acc = {0.f, 0.f};
    for (int e = 0; e < dg; ++e) {
      int s = csr_src[rs + e];
      float w = csr_w[rs + e];
      float2 v = H2[s * 64 + lane];
      acc.x += w * v.x;
      acc.y += w * v.y;
    }
    float wse = di * di;
    float2 vs = H2[wave * 64 + lane];
    acc.x += wse * vs.x + bias[2 * lane];
    acc.y += wse * vs.y + bias[2 * lane + 1];
    ((float2*)outp)[wave * 64 + lane] = acc;
  } else {
    float acc = 0.f;
    for (int e = 0; e < dg; ++e) {
      int s = csr_src[rs + e];
      float w = csr_w[rs + e];
      acc += w * H[s * F + lane];
    }
    acc += di * di * H[wave * F + lane] + bias[lane];
    outp[wave * F + lane] = acc;
  }
}

// ---------------------------------------------------------------- BatchNorm
__global__ void bn_stats_k(const float* __restrict__ A, float* __restrict__ stats, int nrows) {
  int c = threadIdx.x;  // 128 threads = 128 cols
  float s = 0.f, s2 = 0.f;
  for (int r = blockIdx.x; r < nrows; r += gridDim.x) {
    float v = A[r * 128 + c];
    s += v;
    s2 += v * v;
  }
  atomicAdd(&stats[c], s);
  atomicAdd(&stats[128 + c], s2);
}

__global__ void bn_finalize_k(const float* __restrict__ stats, const float* __restrict__ g,
                              const float* __restrict__ be, float* __restrict__ ss) {
  int c = threadIdx.x;
  float mean = stats[c] * (1.f / kN);
  float var = stats[128 + c] * (1.f / kN) - mean * mean;
  float inv = rsqrtf(var + kEps);
  float sc = g[c] * inv;
  ss[c] = sc;
  ss[128 + c] = be[c] - mean * sc;
}

// z = scale[c]*a + shift[c] + r   (float4 over [N,128])
__global__ void bn_apply_res_k(const float* __restrict__ a, const float* __restrict__ r,
                               const float* __restrict__ ss, float* __restrict__ z) {
  int idx = blockIdx.x * blockDim.x + threadIdx.x;
  if (idx >= kN * 32) return;
  float4 av = ((const float4*)a)[idx];
  float4 rv = ((const float4*)r)[idx];
  int c = (idx & 31) * 4;
  float4 o;
  o.x = ss[c + 0] * av.x + ss[128 + c + 0] + rv.x;
  o.y = ss[c + 1] * av.y + ss[128 + c + 1] + rv.y;
  o.z = ss[c + 2] * av.z + ss[128 + c + 2] + rv.z;
  o.w = ss[c + 3] * av.w + ss[128 + c + 3] + rv.w;
  ((float4*)z)[idx] = o;
}

// ---------------------------------------------------------------- launch
extern "C" void kernel_launch(void* const* d_in, const int* in_sizes, int n_in,
                              void* d_out, int out_size, void* d_ws, size_t ws_size,
                              hipStream_t stream) {
  const float* x   = (const float*)d_in[0];
  const int*   ei  = (const int*)d_in[1];
  const float* W1  = (const float*)d_in[2];
  const float* b1  = (const float*)d_in[3];
  const float* g1  = (const float*)d_in[4];
  const float* be1 = (const float*)d_in[5];
  const float* W2  = (const float*)d_in[6];
  const float* b2  = (const float*)d_in[7];
  const float* g2  = (const float*)d_in[8];
  const float* be2 = (const float*)d_in[9];
  const float* W3  = (const float*)d_in[10];
  const float* b3  = (const float*)d_in[11];
  float* outp = (float*)d_out;

  const int* src = ei;
  const int* dst = ei + kE;

  char* ws = (char*)d_ws;
  size_t off = 0;
  auto alloc = [&](size_t bytes) -> void* {
    void* p = ws + off;
    off = (off + bytes + 255) & ~size_t(255);
    return p;
  };
  float* bufA     = (float*)alloc((size_t)kN * 128 * 4);
  float* bufB     = (float*)alloc((size_t)kN * 128 * 4);
  float* bufC     = (float*)alloc((size_t)kN * 128 * 4);
  int*   csr_src  = (int*)alloc((size_t)kE * 4);
  float* csr_w    = (float*)alloc((size_t)kE * 4);
  float* dinv     = (float*)alloc((size_t)kN * 4);
  int*   deg      = (int*)alloc((size_t)kN * 4);
  int*   rowst    = (int*)alloc((size_t)kN * 4);
  int*   cursor   = (int*)alloc((size_t)kN * 4);
  float* stats    = (float*)alloc(256 * 4);
  float* ss       = (float*)alloc(256 * 4);
  int*   counter  = (int*)alloc(4);

  const int TB = 256;
  int blkE = (kE + TB - 1) / TB;
  int blkNn = (kN + TB - 1) / TB;
  int blkGemm = (kN + 127) / 128;
  int blkAgg = (kN + 3) / 4;         // 4 waves/block, 1 wave/node
  int blkEw = (kN * 32 + TB - 1) / TB;

  // CSR build (per launch; ws is re-poisoned each call)
  hipMemsetAsync(deg, 0, (size_t)kN * 4, stream);
  hipMemsetAsync(counter, 0, 4, stream);
  count_deg_k<<<blkE, TB, 0, stream>>>(dst, deg);
  dinv_k<<<blkNn, TB, 0, stream>>>(deg, dinv);
  alloc_rows_k<<<blkNn, TB, 0, stream>>>(deg, rowst, cursor, counter);
  scatter_k<<<blkE, TB, 0, stream>>>(src, dst, dinv, cursor, csr_src, csr_w);

  // Layer 1: h1 = x@W1 ; a1 = agg(h1)+b1 ; z1 = bn(a1)+x  -> bufC
  gemm_k<128, false><<<blkGemm, 256, 0, stream>>>(x, W1, bufA, kN);
  aggregate_k<128><<<blkAgg, TB, 0, stream>>>(bufA, rowst, deg, csr_src, csr_w, dinv, b1, bufB);
  hipMemsetAsync(stats, 0, 256 * 4, stream);
  bn_stats_k<<<512, 128, 0, stream>>>(bufB, stats, kN);
  bn_finalize_k<<<1, 128, 0, stream>>>(stats, g1, be1, ss);
  bn_apply_res_k<<<blkEw, TB, 0, stream>>>(bufB, x, ss, bufC);

  // Layer 2: h2 = relu(z1)@W2 ; a2 = agg(h2)+b2 ; z2 = bn(a2)+z1 -> bufB (in place)
  gemm_k<128, true><<<blkGemm, 256, 0, stream>>>(bufC, W2, bufA, kN);
  aggregate_k<128><<<blkAgg, TB, 0, stream>>>(bufA, rowst, deg, csr_src, csr_w, dinv, b2, bufB);
  hipMemsetAsync(stats, 0, 256 * 4, stream);
  bn_stats_k<<<512, 128, 0, stream>>>(bufB, stats, kN);
  bn_finalize_k<<<1, 128, 0, stream>>>(stats, g2, be2, ss);
  bn_apply_res_k<<<blkEw, TB, 0, stream>>>(bufB, bufC, ss, bufB);

  // Layer 3: h3 = relu(z2)@W3 ; out = agg(h3)+b3 -> d_out
  gemm_k<64, true><<<blkGemm, 128, 0, stream>>>(bufB, W3, bufA, kN);
  aggregate_k<64><<<blkAgg, TB, 0, stream>>>(bufA, rowst, deg, csr_src, csr_w, dinv, b3, outp);
}

// Round 2
// 1021.441 us; speedup vs baseline: 1.5935x; 1.5935x over previous
//
#include <hip/hip_runtime.h>

static constexpr int kN = 100000;
static constexpr int kE = 1600000;
static constexpr float kEps = 1e-5f;

typedef __attribute__((ext_vector_type(8))) short short8;   // 8 bf16 = 4 VGPRs
typedef __attribute__((ext_vector_type(4))) float float4v;  // MFMA acc

static __device__ inline unsigned short f2bf(float f) {
  union { float f; unsigned int u; } v; v.f = f;
  unsigned int r = v.u + 0x7fffu + ((v.u >> 16) & 1u);  // round-to-nearest-even
  return (unsigned short)(r >> 16);
}

// ---------------------------------------------------------------- CSR build
__global__ void count_deg_k(const int* __restrict__ dst, int* __restrict__ deg) {
  int e = blockIdx.x * blockDim.x + threadIdx.x;
  if (e < kE) atomicAdd(&deg[dst[e]], 1);
}

__global__ void dinv_k(const int* __restrict__ deg, float* __restrict__ dinv) {
  int i = blockIdx.x * blockDim.x + threadIdx.x;
  if (i < kN) dinv[i] = rsqrtf((float)(deg[i] + 1));  // +1 self-loop
}

__global__ void alloc_rows_k(const int* __restrict__ deg, int* __restrict__ row_start,
                             int* __restrict__ cursor, int* __restrict__ counter) {
  int i = blockIdx.x * blockDim.x + threadIdx.x;
  int lane = threadIdx.x & 63;
  int d = (i < kN) ? deg[i] : 0;
  int x = d;
  #pragma unroll
  for (int off = 1; off < 64; off <<= 1) {
    int y = __shfl_up(x, off, 64);
    if (lane >= off) x += y;
  }
  int total = __shfl(x, 63, 64);
  int base = 0;
  if (lane == 63) base = atomicAdd(counter, total);
  base = __shfl(base, 63, 64);
  int start = base + x - d;
  if (i < kN) { row_start[i] = start; cursor[i] = start; }
}

__global__ void scatter_k(const int* __restrict__ src, const int* __restrict__ dst,
                          const float* __restrict__ dinv, int* __restrict__ cursor,
                          int* __restrict__ csr_src, float* __restrict__ csr_w) {
  int e = blockIdx.x * blockDim.x + threadIdx.x;
  if (e >= kE) return;
  int s = src[e], d = dst[e];
  int pos = atomicAdd(&cursor[d], 1);
  csr_src[pos] = s;
  csr_w[pos] = dinv[s] * dinv[d];
}

// ---------------------------------------------------------------- dtype converts
// x fp32 -> bf16 row-major
__global__ void convert_x_k(const float* __restrict__ X, unsigned short* __restrict__ Xb) {
  int i = blockIdx.x * blockDim.x + threadIdx.x;
  if (i >= kN * 32) return;
  float4 xv = ((const float4*)X)[i];
  ushort4 o;
  o.x = f2bf(xv.x); o.y = f2bf(xv.y); o.z = f2bf(xv.z); o.w = f2bf(xv.w);
  ((ushort4*)Xb)[i] = o;
}

// W [128 x BNO] fp32 -> bf16 in MFMA B-fragment order.
// frag = t*4 + q  (t = n-tile of 16, q = k-tile of 32); lane l holds
// B[k = q*32 + (l>>4)*8 + j][n = t*16 + (l&15)], j=0..7 contiguous.
template <int BNO>
__global__ void convert_w_k(const float* __restrict__ W, unsigned short* __restrict__ Wf) {
  constexpr int NFRAG = (BNO / 16) * 4;
  int tid = blockIdx.x * blockDim.x + threadIdx.x;
  if (tid >= NFRAG * 64) return;
  int l = tid & 63;
  int frag = tid >> 6;
  int q = frag & 3;
  int t = frag >> 2;
  int n = t * 16 + (l & 15);
  int kbase = q * 32 + ((l >> 4) << 3);
  unsigned short v[8] __attribute__((aligned(16)));
  #pragma unroll
  for (int j = 0; j < 8; ++j) v[j] = f2bf(W[(kbase + j) * BNO + n]);
  ((uint4*)Wf)[tid] = *(const uint4*)v;
}

// ---------------------------------------------------------------- MFMA GEMM
// C[N x BNO] fp32 = A_bf16[N x 128] @ W_frag_bf16[128 x BNO]
// One wave per 16-row strip; A frags straight from global; W frags L2-hot.
template <int BNO>
__global__ __launch_bounds__(256) void gemm_mfma_k(const unsigned short* __restrict__ Ab,
                                                   const unsigned short* __restrict__ Wf,
                                                   float* __restrict__ C) {
  int wid = (int)((blockIdx.x * blockDim.x + threadIdx.x) >> 6);
  if (wid >= kN / 16) return;  // 100000 = 16 * 6250 exactly
  int l = threadIdx.x & 63;
  int r0 = wid * 16;
  // A-fragment: lane holds A[m = l&15][k = q*32 + (l>>4)*8 + j]
  const short8* Arow = (const short8*)(Ab + (size_t)(r0 + (l & 15)) * 128 + ((l >> 4) << 3));
  short8 a[4];
  #pragma unroll
  for (int q = 0; q < 4; ++q) a[q] = Arow[q * 4];  // q*32 shorts = q*4 short8
  const short8* Wv = (const short8*)Wf + l;
  constexpr int NT = BNO / 16;
  float4v acc[NT];
  #pragma unroll
  for (int t = 0; t < NT; ++t) {
    acc[t] = (float4v){0.f, 0.f, 0.f, 0.f};
    #pragma unroll
    for (int q = 0; q < 4; ++q) {
      short8 b = Wv[(t * 4 + q) * 64];
      acc[t] = __builtin_amdgcn_mfma_f32_16x16x32_bf16(a[q], b, acc[t], 0, 0, 0);
    }
  }
  // C/D layout: col = l&15, row = (l>>4)*4 + reg
  int orow = r0 + ((l >> 4) << 2);
  int ocol = l & 15;
  #pragma unroll
  for (int t = 0; t < NT; ++t) {
    #pragma unroll
    for (int r = 0; r < 4; ++r) {
      C[(size_t)(orow + r) * BNO + t * 16 + ocol] = acc[t][r];
    }
  }
}

// ---------------------------------------------------------------- aggregation (gather, 1 wave/node)
template <int F>
__global__ void aggregate_k(const float* __restrict__ H,
                            const int* __restrict__ row_start,
                            const int* __restrict__ deg,
                            const int* __restrict__ csr_src,
                            const float* __restrict__ csr_w,
                            const float* __restrict__ dinv,
                            const float* __restrict__ bias,
                            float* __restrict__ outp) {
  int wave = (int)((blockIdx.x * blockDim.x + threadIdx.x) >> 6);
  if (wave >= kN) return;
  int lane = threadIdx.x & 63;
  int rs = row_start[wave];
  int dg = deg[wave];
  float di = dinv[wave];
  if constexpr (F == 128) {
    const float2* H2 = (const float2*)H;
    float2 acc = {0.f, 0.f};
    for (int e = 0; e < dg; ++e) {
      int s = csr_src[rs + e];
      float w = csr_w[rs + e];
      float2 v = H2[s * 64 + lane];
      acc.x += w * v.x;
      acc.y += w * v.y;
    }
    float wse = di * di;
    float2 vs = H2[wave * 64 + lane];
    acc.x += wse * vs.x + bias[2 * lane];
    acc.y += wse * vs.y + bias[2 * lane + 1];
    ((float2*)outp)[wave * 64 + lane] = acc;
  } else {
    float acc = 0.f;
    for (int e = 0; e < dg; ++e) {
      int s = csr_src[rs + e];
      float w = csr_w[rs + e];
      acc += w * H[s * F + lane];
    }
    acc += di * di * H[wave * F + lane] + bias[lane];
    outp[wave * F + lane] = acc;
  }
}

// ---------------------------------------------------------------- BatchNorm
__global__ void bn_stats_k(const float* __restrict__ A, float* __restrict__ stats, int nrows) {
  int c = threadIdx.x;
  float s = 0.f, s2 = 0.f;
  for (int r = blockIdx.x; r < nrows; r += gridDim.x) {
    float v = A[r * 128 + c];
    s += v;
    s2 += v * v;
  }
  atomicAdd(&stats[c], s);
  atomicAdd(&stats[128 + c], s2);
}

__global__ void bn_finalize_k(const float* __restrict__ stats, const float* __restrict__ g,
                              const float* __restrict__ be, float* __restrict__ ss) {
  int c = threadIdx.x;
  float mean = stats[c] * (1.f / kN);
  float var = stats[128 + c] * (1.f / kN) - mean * mean;
  float inv = rsqrtf(var + kEps);
  float sc = g[c] * inv;
  ss[c] = sc;
  ss[128 + c] = be[c] - mean * sc;
}

// z = scale[c]*a + shift[c] + r ; optionally store z fp32; always store bf16(relu(z))
template <bool WRITE_Z>
__global__ void bn_apply_res_fused_k(const float* __restrict__ a, const float* __restrict__ r,
                                     const float* __restrict__ ss, float* __restrict__ z,
                                     unsigned short* __restrict__ rb) {
  int idx = blockIdx.x * blockDim.x + threadIdx.x;
  if (idx >= kN * 32) return;
  float4 av = ((const float4*)a)[idx];
  float4 rv = ((const float4*)r)[idx];
  int c = (idx & 31) * 4;
  float4 o;
  o.x = ss[c + 0] * av.x + ss[128 + c + 0] + rv.x;
  o.y = ss[c + 1] * av.y + ss[128 + c + 1] + rv.y;
  o.z = ss[c + 2] * av.z + ss[128 + c + 2] + rv.z;
  o.w = ss[c + 3] * av.w + ss[128 + c + 3] + rv.w;
  if (WRITE_Z) ((float4*)z)[idx] = o;
  ushort4 ob;
  ob.x = f2bf(fmaxf(o.x, 0.f));
  ob.y = f2bf(fmaxf(o.y, 0.f));
  ob.z = f2bf(fmaxf(o.z, 0.f));
  ob.w = f2bf(fmaxf(o.w, 0.f));
  ((ushort4*)rb)[idx] = ob;
}

// ---------------------------------------------------------------- launch
extern "C" void kernel_launch(void* const* d_in, const int* in_sizes, int n_in,
                              void* d_out, int out_size, void* d_ws, size_t ws_size,
                              hipStream_t stream) {
  const float* x   = (const float*)d_in[0];
  const int*   ei  = (const int*)d_in[1];
  const float* W1  = (const float*)d_in[2];
  const float* b1  = (const float*)d_in[3];
  const float* g1  = (const float*)d_in[4];
  const float* be1 = (const float*)d_in[5];
  const float* W2  = (const float*)d_in[6];
  const float* b2  = (const float*)d_in[7];
  const float* g2  = (const float*)d_in[8];
  const float* be2 = (const float*)d_in[9];
  const float* W3  = (const float*)d_in[10];
  const float* b3  = (const float*)d_in[11];
  float* outp = (float*)d_out;

  const int* src = ei;
  const int* dst = ei + kE;

  char* ws = (char*)d_ws;
  size_t off = 0;
  auto alloc = [&](size_t bytes) -> void* {
    void* p = ws + off;
    off = (off + bytes + 255) & ~size_t(255);
    return p;
  };
  float* bufA     = (float*)alloc((size_t)kN * 128 * 4);   // gemm out / agg in
  float* bufB     = (float*)alloc((size_t)kN * 128 * 4);   // agg out / bn in
  float* bufC     = (float*)alloc((size_t)kN * 128 * 4);   // z1 residual
  unsigned short* hb = (unsigned short*)alloc((size_t)kN * 128 * 2);  // bf16 gemm input
  int*   csr_src  = (int*)alloc((size_t)kE * 4);
  float* csr_w    = (float*)alloc((size_t)kE * 4);
  float* dinv     = (float*)alloc((size_t)kN * 4);
  int*   deg      = (int*)alloc((size_t)kN * 4);
  int*   rowst    = (int*)alloc((size_t)kN * 4);
  int*   cursor   = (int*)alloc((size_t)kN * 4);
  float* stats    = (float*)alloc(256 * 4);
  float* ss       = (float*)alloc(256 * 4);
  int*   counter  = (int*)alloc(4);
  unsigned short* wf1 = (unsigned short*)alloc(128 * 128 * 2);
  unsigned short* wf2 = (unsigned short*)alloc(128 * 128 * 2);
  unsigned short* wf3 = (unsigned short*)alloc(128 * 64 * 2);

  const int TB = 256;
  int blkE = (kE + TB - 1) / TB;
  int blkNn = (kN + TB - 1) / TB;
  int blkAgg = (kN + 3) / 4;
  int blkEw = (kN * 32 + TB - 1) / TB;
  int blkGemm = (kN / 16 + 3) / 4;   // 1 wave per 16-row strip, 4 waves/block

  // CSR build
  hipMemsetAsync(deg, 0, (size_t)kN * 4, stream);
  hipMemsetAsync(counter, 0, 4, stream);
  count_deg_k<<<blkE, TB, 0, stream>>>(dst, deg);
  dinv_k<<<blkNn, TB, 0, stream>>>(deg, dinv);
  alloc_rows_k<<<blkNn, TB, 0, stream>>>(deg, rowst, cursor, counter);
  scatter_k<<<blkE, TB, 0, stream>>>(src, dst, dinv, cursor, csr_src, csr_w);

  // weight + input converts
  convert_w_k<128><<<(2048 + TB - 1) / TB, TB, 0, stream>>>(W1, wf1);
  convert_w_k<128><<<(2048 + TB - 1) / TB, TB, 0, stream>>>(W2, wf2);
  convert_w_k<64><<<(1024 + TB - 1) / TB, TB, 0, stream>>>(W3, wf3);
  convert_x_k<<<blkEw, TB, 0, stream>>>(x, hb);

  // Layer 1
  gemm_mfma_k<128><<<blkGemm, 256, 0, stream>>>(hb, wf1, bufA);
  aggregate_k<128><<<blkAgg, TB, 0, stream>>>(bufA, rowst, deg, csr_src, csr_w, dinv, b1, bufB);
  hipMemsetAsync(stats, 0, 256 * 4, stream);
  bn_stats_k<<<512, 128, 0, stream>>>(bufB, stats, kN);
  bn_finalize_k<<<1, 128, 0, stream>>>(stats, g1, be1, ss);
  bn_apply_res_fused_k<true><<<blkEw, TB, 0, stream>>>(bufB, x, ss, bufC, hb);

  // Layer 2
  gemm_mfma_k<128><<<blkGemm, 256, 0, stream>>>(hb, wf2, bufA);
  aggregate_k<128><<<blkAgg, TB, 0, stream>>>(bufA, rowst, deg, csr_src, csr_w, dinv, b2, bufB);
  hipMemsetAsync(stats, 0, 256 * 4, stream);
  bn_stats_k<<<512, 128, 0, stream>>>(bufB, stats, kN);
  bn_finalize_k<<<1, 128, 0, stream>>>(stats, g2, be2, ss);
  bn_apply_res_fused_k<false><<<blkEw, TB, 0, stream>>>(bufB, bufC, ss, nullptr, hb);

  // Layer 3
  gemm_mfma_k<64><<<blkGemm, 256, 0, stream>>>(hb, wf3, bufA);
  aggregate_k<64><<<blkAgg, TB, 0, stream>>>(bufA, rowst, deg, csr_src, csr_w, dinv, b3, outp);
}

// Round 3
// 716.534 us; speedup vs baseline: 2.2716x; 1.4255x over previous
//
#include <hip/hip_runtime.h>

static constexpr int kN = 100000;
static constexpr int kE = 1600000;
static constexpr float kEps = 1e-5f;

typedef __attribute__((ext_vector_type(8))) short short8;   // 8 bf16 = 4 VGPRs
typedef __attribute__((ext_vector_type(4))) float float4v;  // MFMA acc

static __device__ inline unsigned short f2bf(float f) {
  union { float f; unsigned int u; } v; v.f = f;
  unsigned int r = v.u + 0x7fffu + ((v.u >> 16) & 1u);  // RNE
  return (unsigned short)(r >> 16);
}
static __device__ inline float bf2f(unsigned int bits16) {
  union { unsigned int u; float f; } v; v.u = bits16 << 16; return v.f;
}

// ---------------------------------------------------------------- CSR build
__global__ void count_deg_k(const int* __restrict__ dst, int* __restrict__ deg) {
  int e = blockIdx.x * blockDim.x + threadIdx.x;
  if (e < kE) atomicAdd(&deg[dst[e]], 1);
}

__global__ void dinv_k(const int* __restrict__ deg, float* __restrict__ dinv) {
  int i = blockIdx.x * blockDim.x + threadIdx.x;
  if (i < kN) dinv[i] = rsqrtf((float)(deg[i] + 1));  // +1 self-loop
}

__global__ void alloc_rows_k(const int* __restrict__ deg, int* __restrict__ row_start,
                             int* __restrict__ cursor, int* __restrict__ counter) {
  int i = blockIdx.x * blockDim.x + threadIdx.x;
  int lane = threadIdx.x & 63;
  int d = (i < kN) ? deg[i] : 0;
  int x = d;
  #pragma unroll
  for (int off = 1; off < 64; off <<= 1) {
    int y = __shfl_up(x, off, 64);
    if (lane >= off) x += y;
  }
  int total = __shfl(x, 63, 64);
  int base = 0;
  if (lane == 63) base = atomicAdd(counter, total);
  base = __shfl(base, 63, 64);
  int start = base + x - d;
  if (i < kN) { row_start[i] = start; cursor[i] = start; }
}

__global__ void scatter_k(const int* __restrict__ src, const int* __restrict__ dst,
                          const float* __restrict__ dinv, int* __restrict__ cursor,
                          int* __restrict__ csr_src, float* __restrict__ csr_w) {
  int e = blockIdx.x * blockDim.x + threadIdx.x;
  if (e >= kE) return;
  int s = src[e], d = dst[e];
  int pos = atomicAdd(&cursor[d], 1);
  csr_src[pos] = s;
  csr_w[pos] = dinv[s] * dinv[d];
}

// ---------------------------------------------------------------- dtype converts
__global__ void convert_x_k(const float* __restrict__ X, unsigned short* __restrict__ Xb) {
  int i = blockIdx.x * blockDim.x + threadIdx.x;
  if (i >= kN * 32) return;
  float4 xv = ((const float4*)X)[i];
  ushort4 o;
  o.x = f2bf(xv.x); o.y = f2bf(xv.y); o.z = f2bf(xv.z); o.w = f2bf(xv.w);
  ((ushort4*)Xb)[i] = o;
}

// W [128 x BNO] fp32 -> bf16 in MFMA B-fragment order.
template <int BNO>
__global__ void convert_w_k(const float* __restrict__ W, unsigned short* __restrict__ Wf) {
  constexpr int NFRAG = (BNO / 16) * 4;
  int tid = blockIdx.x * blockDim.x + threadIdx.x;
  if (tid >= NFRAG * 64) return;
  int l = tid & 63;
  int frag = tid >> 6;
  int q = frag & 3;
  int t = frag >> 2;
  int n = t * 16 + (l & 15);
  int kbase = q * 32 + ((l >> 4) << 3);
  unsigned short v[8] __attribute__((aligned(16)));
  #pragma unroll
  for (int j = 0; j < 8; ++j) v[j] = f2bf(W[(kbase + j) * BNO + n]);
  ((uint4*)Wf)[tid] = *(const uint4*)v;
}

// ---------------------------------------------------------------- MFMA GEMM -> bf16 out
template <int BNO>
__global__ __launch_bounds__(256) void gemm_mfma_k(const unsigned short* __restrict__ Ab,
                                                   const unsigned short* __restrict__ Wf,
                                                   unsigned short* __restrict__ C) {
  int wid = (int)((blockIdx.x * blockDim.x + threadIdx.x) >> 6);
  if (wid >= kN / 16) return;  // 100000 = 16 * 6250
  int l = threadIdx.x & 63;
  int r0 = wid * 16;
  const short8* Arow = (const short8*)(Ab + (size_t)(r0 + (l & 15)) * 128 + ((l >> 4) << 3));
  short8 a[4];
  #pragma unroll
  for (int q = 0; q < 4; ++q) a[q] = Arow[q * 4];
  const short8* Wv = (const short8*)Wf + l;
  constexpr int NT = BNO / 16;
  float4v acc[NT];
  #pragma unroll
  for (int t = 0; t < NT; ++t) {
    acc[t] = (float4v){0.f, 0.f, 0.f, 0.f};
    #pragma unroll
    for (int q = 0; q < 4; ++q) {
      short8 b = Wv[(t * 4 + q) * 64];
      acc[t] = __builtin_amdgcn_mfma_f32_16x16x32_bf16(a[q], b, acc[t], 0, 0, 0);
    }
  }
  int orow = r0 + ((l >> 4) << 2);
  int ocol = l & 15;
  #pragma unroll
  for (int t = 0; t < NT; ++t) {
    #pragma unroll
    for (int r = 0; r < 4; ++r) {
      C[(size_t)(orow + r) * BNO + t * 16 + ocol] = f2bf(acc[t][r]);
    }
  }
}

// ---------------------------------------------------------------- aggregation
// Gather bf16 H rows, fp32 accumulate, write fp32; optional fused BN-stats.
// Grid-stride: one wave per node per step.
template <bool STATS>
__global__ __launch_bounds__(256) void aggregate128_k(
    const unsigned short* __restrict__ Hb, const int* __restrict__ row_start,
    const int* __restrict__ deg, const int* __restrict__ csr_src,
    const float* __restrict__ csr_w, const float* __restrict__ dinv,
    const float* __restrict__ bias, float* __restrict__ outp,
    float* __restrict__ stats) {
  __shared__ float s_sum[128], s_sq[128];
  int tid = threadIdx.x;
  if (STATS) {
    if (tid < 128) { s_sum[tid] = 0.f; s_sq[tid] = 0.f; }
    __syncthreads();
  }
  int lane = tid & 63;
  int nwaves = gridDim.x * (blockDim.x >> 6);
  int gwave = (int)((blockIdx.x * blockDim.x + tid) >> 6);
  const unsigned int* Hu = (const unsigned int*)Hb;  // 2 bf16 per uint, 64/row
  float bx = bias[2 * lane], by = bias[2 * lane + 1];
  float sx = 0.f, sy = 0.f, qx = 0.f, qy = 0.f;
  for (int node = gwave; node < kN; node += nwaves) {
    int rs = row_start[node];
    int dg = deg[node];
    float di = dinv[node];
    float ax = 0.f, ay = 0.f;
    int e = rs, end = rs + dg;
    for (; e + 4 <= end; e += 4) {
      int s0 = csr_src[e], s1 = csr_src[e + 1], s2 = csr_src[e + 2], s3 = csr_src[e + 3];
      float w0 = csr_w[e], w1 = csr_w[e + 1], w2 = csr_w[e + 2], w3 = csr_w[e + 3];
      unsigned int v0 = Hu[(size_t)s0 * 64 + lane];
      unsigned int v1 = Hu[(size_t)s1 * 64 + lane];
      unsigned int v2 = Hu[(size_t)s2 * 64 + lane];
      unsigned int v3 = Hu[(size_t)s3 * 64 + lane];
      ax += w0 * bf2f(v0 & 0xffffu); ay += w0 * bf2f(v0 >> 16);
      ax += w1 * bf2f(v1 & 0xffffu); ay += w1 * bf2f(v1 >> 16);
      ax += w2 * bf2f(v2 & 0xffffu); ay += w2 * bf2f(v2 >> 16);
      ax += w3 * bf2f(v3 & 0xffffu); ay += w3 * bf2f(v3 >> 16);
    }
    for (; e < end; ++e) {
      int s = csr_src[e];
      float w = csr_w[e];
      unsigned int v = Hu[(size_t)s * 64 + lane];
      ax += w * bf2f(v & 0xffffu); ay += w * bf2f(v >> 16);
    }
    unsigned int vs = Hu[(size_t)node * 64 + lane];
    float wse = di * di;
    float ox = ax + wse * bf2f(vs & 0xffffu) + bx;
    float oy = ay + wse * bf2f(vs >> 16) + by;
    ((float2*)outp)[(size_t)node * 64 + lane] = make_float2(ox, oy);
    if (STATS) { sx += ox; sy += oy; qx += ox * ox; qy += oy * oy; }
  }
  if (STATS) {
    atomicAdd(&s_sum[2 * lane], sx);
    atomicAdd(&s_sum[2 * lane + 1], sy);
    atomicAdd(&s_sq[2 * lane], qx);
    atomicAdd(&s_sq[2 * lane + 1], qy);
    __syncthreads();
    if (tid < 128) {
      atomicAdd(&stats[tid], s_sum[tid]);
      atomicAdd(&stats[128 + tid], s_sq[tid]);
    }
  }
}

// F=64 final layer: gather bf16, write fp32 out (+bias), no stats.
__global__ __launch_bounds__(256) void aggregate64_k(
    const unsigned short* __restrict__ Hb, const int* __restrict__ row_start,
    const int* __restrict__ deg, const int* __restrict__ csr_src,
    const float* __restrict__ csr_w, const float* __restrict__ dinv,
    const float* __restrict__ bias, float* __restrict__ outp) {
  int lane = threadIdx.x & 63;
  int nwaves = gridDim.x * (blockDim.x >> 6);
  int gwave = (int)((blockIdx.x * blockDim.x + threadIdx.x) >> 6);
  float b = bias[lane];
  for (int node = gwave; node < kN; node += nwaves) {
    int rs = row_start[node];
    int dg = deg[node];
    float di = dinv[node];
    float acc = 0.f;
    int e = rs, end = rs + dg;
    for (; e + 4 <= end; e += 4) {
      int s0 = csr_src[e], s1 = csr_src[e + 1], s2 = csr_src[e + 2], s3 = csr_src[e + 3];
      float w0 = csr_w[e], w1 = csr_w[e + 1], w2 = csr_w[e + 2], w3 = csr_w[e + 3];
      float v0 = bf2f(Hb[(size_t)s0 * 64 + lane]);
      float v1 = bf2f(Hb[(size_t)s1 * 64 + lane]);
      float v2 = bf2f(Hb[(size_t)s2 * 64 + lane]);
      float v3 = bf2f(Hb[(size_t)s3 * 64 + lane]);
      acc += w0 * v0 + w1 * v1 + w2 * v2 + w3 * v3;
    }
    for (; e < end; ++e) {
      acc += csr_w[e] * bf2f(Hb[(size_t)csr_src[e] * 64 + lane]);
    }
    acc += di * di * bf2f(Hb[(size_t)node * 64 + lane]) + b;
    outp[(size_t)node * 64 + lane] = acc;
  }
}

// ---------------------------------------------------------------- BatchNorm
__global__ void bn_finalize_k(const float* __restrict__ stats, const float* __restrict__ g,
                              const float* __restrict__ be, float* __restrict__ ss) {
  int c = threadIdx.x;
  float mean = stats[c] * (1.f / kN);
  float var = stats[128 + c] * (1.f / kN) - mean * mean;
  float inv = rsqrtf(var + kEps);
  float sc = g[c] * inv;
  ss[c] = sc;
  ss[128 + c] = be[c] - mean * sc;
}

// z = scale[c]*a + shift[c] + r ; optional fp32 z store; always bf16(relu(z))
template <bool WRITE_Z>
__global__ void bn_apply_res_fused_k(const float* __restrict__ a, const float* __restrict__ r,
                                     const float* __restrict__ ss, float* __restrict__ z,
                                     unsigned short* __restrict__ rb) {
  int idx = blockIdx.x * blockDim.x + threadIdx.x;
  if (idx >= kN * 32) return;
  float4 av = ((const float4*)a)[idx];
  float4 rv = ((const float4*)r)[idx];
  int c = (idx & 31) * 4;
  float4 o;
  o.x = ss[c + 0] * av.x + ss[128 + c + 0] + rv.x;
  o.y = ss[c + 1] * av.y + ss[128 + c + 1] + rv.y;
  o.z = ss[c + 2] * av.z + ss[128 + c + 2] + rv.z;
  o.w = ss[c + 3] * av.w + ss[128 + c + 3] + rv.w;
  if (WRITE_Z) ((float4*)z)[idx] = o;
  ushort4 ob;
  ob.x = f2bf(fmaxf(o.x, 0.f));
  ob.y = f2bf(fmaxf(o.y, 0.f));
  ob.z = f2bf(fmaxf(o.z, 0.f));
  ob.w = f2bf(fmaxf(o.w, 0.f));
  ((ushort4*)rb)[idx] = ob;
}

// ---------------------------------------------------------------- launch
extern "C" void kernel_launch(void* const* d_in, const int* in_sizes, int n_in,
                              void* d_out, int out_size, void* d_ws, size_t ws_size,
                              hipStream_t stream) {
  const float* x   = (const float*)d_in[0];
  const int*   ei  = (const int*)d_in[1];
  const float* W1  = (const float*)d_in[2];
  const float* b1  = (const float*)d_in[3];
  const float* g1  = (const float*)d_in[4];
  const float* be1 = (const float*)d_in[5];
  const float* W2  = (const float*)d_in[6];
  const float* b2  = (const float*)d_in[7];
  const float* g2  = (const float*)d_in[8];
  const float* be2 = (const float*)d_in[9];
  const float* W3  = (const float*)d_in[10];
  const float* b3  = (const float*)d_in[11];
  float* outp = (float*)d_out;

  const int* src = ei;
  const int* dst = ei + kE;

  char* ws = (char*)d_ws;
  size_t off = 0;
  auto alloc = [&](size_t bytes) -> void* {
    void* p = ws + off;
    off = (off + bytes + 255) & ~size_t(255);
    return p;
  };
  unsigned short* hH = (unsigned short*)alloc((size_t)kN * 128 * 2);  // bf16 gemm out
  float* bufB     = (float*)alloc((size_t)kN * 128 * 4);   // agg out / bn in
  float* bufC     = (float*)alloc((size_t)kN * 128 * 4);   // z1 residual
  unsigned short* hb = (unsigned short*)alloc((size_t)kN * 128 * 2);  // bf16 gemm in
  int*   csr_src  = (int*)alloc((size_t)kE * 4);
  float* csr_w    = (float*)alloc((size_t)kE * 4);
  float* dinv     = (float*)alloc((size_t)kN * 4);
  int*   deg      = (int*)alloc((size_t)kN * 4);
  int*   rowst    = (int*)alloc((size_t)kN * 4);
  int*   cursor   = (int*)alloc((size_t)kN * 4);
  float* stats    = (float*)alloc(256 * 4);
  float* ss       = (float*)alloc(256 * 4);
  int*   counter  = (int*)alloc(4);
  unsigned short* wf1 = (unsigned short*)alloc(128 * 128 * 2);
  unsigned short* wf2 = (unsigned short*)alloc(128 * 128 * 2);
  unsigned short* wf3 = (unsigned short*)alloc(128 * 64 * 2);

  const int TB = 256;
  int blkE = (kE + TB - 1) / TB;
  int blkNn = (kN + TB - 1) / TB;
  int blkEw = (kN * 32 + TB - 1) / TB;
  int blkGemm = (kN / 16 + 3) / 4;
  const int blkAgg = 2048;  // grid-stride: 8192 waves, ~12 nodes each

  // CSR build
  hipMemsetAsync(deg, 0, (size_t)kN * 4, stream);
  hipMemsetAsync(counter, 0, 4, stream);
  count_deg_k<<<blkE, TB, 0, stream>>>(dst, deg);
  dinv_k<<<blkNn, TB, 0, stream>>>(deg, dinv);
  alloc_rows_k<<<blkNn, TB, 0, stream>>>(deg, rowst, cursor, counter);
  scatter_k<<<blkE, TB, 0, stream>>>(src, dst, dinv, cursor, csr_src, csr_w);

  // converts
  convert_w_k<128><<<(2048 + TB - 1) / TB, TB, 0, stream>>>(W1, wf1);
  convert_w_k<128><<<(2048 + TB - 1) / TB, TB, 0, stream>>>(W2, wf2);
  convert_w_k<64><<<(1024 + TB - 1) / TB, TB, 0, stream>>>(W3, wf3);
  convert_x_k<<<blkEw, TB, 0, stream>>>(x, hb);

  // Layer 1
  hipMemsetAsync(stats, 0, 256 * 4, stream);
  gemm_mfma_k<128><<<blkGemm, 256, 0, stream>>>(hb, wf1, hH);
  aggregate128_k<true><<<blkAgg, TB, 0, stream>>>(hH, rowst, deg, csr_src, csr_w, dinv, b1, bufB, stats);
  bn_finalize_k<<<1, 128, 0, stream>>>(stats, g1, be1, ss);
  bn_apply_res_fused_k<true><<<blkEw, TB, 0, stream>>>(bufB, x, ss, bufC, hb);

  // Layer 2
  hipMemsetAsync(stats, 0, 256 * 4, stream);
  gemm_mfma_k<128><<<blkGemm, 256, 0, stream>>>(hb, wf2, hH);
  aggregate128_k<true><<<blkAgg, TB, 0, stream>>>(hH, rowst, deg, csr_src, csr_w, dinv, b2, bufB, stats);
  bn_finalize_k<<<1, 128, 0, stream>>>(stats, g2, be2, ss);
  bn_apply_res_fused_k<false><<<blkEw, TB, 0, stream>>>(bufB, bufC, ss, nullptr, hb);

  // Layer 3
  gemm_mfma_k<64><<<blkGemm, 256, 0, stream>>>(hb, wf3, hH);
  aggregate64_k<<<blkAgg, TB, 0, stream>>>(hH, rowst, deg, csr_src, csr_w, dinv, b3, outp);
}

// Round 5
// 637.429 us; speedup vs baseline: 2.5535x; 1.1241x over previous
//
#include <hip/hip_runtime.h>

static constexpr int kN = 100000;
static constexpr int kE = 1600000;
static constexpr float kEps = 1e-5f;

typedef __attribute__((ext_vector_type(8))) short short8;   // 8 bf16 = 4 VGPRs
typedef __attribute__((ext_vector_type(4))) float float4v;  // MFMA acc

static __device__ inline unsigned short f2bf(float f) {
  union { float f; unsigned int u; } v; v.f = f;
  unsigned int r = v.u + 0x7fffu + ((v.u >> 16) & 1u);  // RNE
  return (unsigned short)(r >> 16);
}
static __device__ inline float bf2f(unsigned int bits16) {
  union { unsigned int u; float f; } v; v.u = bits16 << 16; return v.f;
}
static __device__ inline unsigned int pack2bf(float lo, float hi) {
  return (unsigned int)f2bf(lo) | ((unsigned int)f2bf(hi) << 16);
}

// ---------------------------------------------------------------- CSR build
__global__ void count_deg_k(const int* __restrict__ dst, int* __restrict__ deg,
                            int* __restrict__ counter) {
  int e = blockIdx.x * blockDim.x + threadIdx.x;
  if (e == 0) *counter = 0;  // consumed later by alloc_rows (stream-ordered)
  if (e < kE) atomicAdd(&deg[dst[e]], 1);
}

// row starts via wave-scan bump allocation; also computes dinv.
__global__ void alloc_rows_k(const int* __restrict__ deg, int* __restrict__ row_start,
                             int* __restrict__ cursor, int* __restrict__ counter,
                             float* __restrict__ dinv) {
  int i = blockIdx.x * blockDim.x + threadIdx.x;
  int lane = threadIdx.x & 63;
  int d = (i < kN) ? deg[i] : 0;
  int x = d;
  #pragma unroll
  for (int off = 1; off < 64; off <<= 1) {
    int y = __shfl_up(x, off, 64);
    if (lane >= off) x += y;
  }
  int total = __shfl(x, 63, 64);
  int base = 0;
  if (lane == 63) base = atomicAdd(counter, total);
  base = __shfl(base, 63, 64);
  int start = base + x - d;
  if (i < kN) {
    row_start[i] = start;
    cursor[i] = start;
    dinv[i] = rsqrtf((float)(d + 1));
  }
}

__global__ void scatter_k(const int* __restrict__ src, const int* __restrict__ dst,
                          const float* __restrict__ dinv, int* __restrict__ cursor,
                          int* __restrict__ csr_src, float* __restrict__ csr_w) {
  int e = blockIdx.x * blockDim.x + threadIdx.x;
  if (e >= kE) return;
  int s = src[e], d = dst[e];
  int pos = atomicAdd(&cursor[d], 1);
  csr_src[pos] = s;
  csr_w[pos] = dinv[s] * dinv[d];
}

// ---------------------------------------------------------------- weight convert (all 3)
// fp32 [128 x BNO] -> bf16 MFMA B-fragment order; frag=t*4+q, lane l holds
// B[k=q*32+(l>>4)*8+j][n=t*16+(l&15)], j=0..7.
__global__ void convert_w_all_k(const float* __restrict__ W1, const float* __restrict__ W2,
                                const float* __restrict__ W3,
                                unsigned short* __restrict__ wf1,
                                unsigned short* __restrict__ wf2,
                                unsigned short* __restrict__ wf3) {
  int tid = blockIdx.x * blockDim.x + threadIdx.x;
  const float* W;
  unsigned short* Wf;
  int BNO;
  if (tid < 2048) { W = W1; Wf = wf1; BNO = 128; }
  else if (tid < 4096) { W = W2; Wf = wf2; BNO = 128; tid -= 2048; }
  else if (tid < 5120) { W = W3; Wf = wf3; BNO = 64; tid -= 4096; }
  else return;
  int l = tid & 63;
  int frag = tid >> 6;
  int q = frag & 3;
  int t = frag >> 2;
  int n = t * 16 + (l & 15);
  int kbase = q * 32 + ((l >> 4) << 3);
  unsigned short v[8] __attribute__((aligned(16)));
  #pragma unroll
  for (int j = 0; j < 8; ++j) v[j] = f2bf(W[(kbase + j) * BNO + n]);
  ((uint4*)Wf)[tid] = *(const uint4*)v;
}

// ---------------------------------------------------------------- MFMA GEMM -> bf16 out
// AF32: A is fp32 row-major (converted in the fragment load); else bf16 row-major.
template <int BNO, bool AF32>
__global__ __launch_bounds__(256) void gemm_mfma_k(const void* __restrict__ Aptr,
                                                   const unsigned short* __restrict__ Wf,
                                                   unsigned short* __restrict__ C,
                                                   float* __restrict__ stats) {
  if (stats && blockIdx.x == 0) stats[threadIdx.x] = 0.f;  // 256 entries, block=256
  int wid = (int)((blockIdx.x * blockDim.x + threadIdx.x) >> 6);
  if (wid >= kN / 16) return;  // 100000 = 16 * 6250
  int l = threadIdx.x & 63;
  int r0 = wid * 16;
  short8 a[4];
  if constexpr (AF32) {
    const float* Af = (const float*)Aptr + (size_t)(r0 + (l & 15)) * 128 + ((l >> 4) << 3);
    #pragma unroll
    for (int q = 0; q < 4; ++q) {
      float4 u0 = *(const float4*)(Af + q * 32);
      float4 u1 = *(const float4*)(Af + q * 32 + 4);
      short8 t;
      t[0] = (short)f2bf(u0.x); t[1] = (short)f2bf(u0.y);
      t[2] = (short)f2bf(u0.z); t[3] = (short)f2bf(u0.w);
      t[4] = (short)f2bf(u1.x); t[5] = (short)f2bf(u1.y);
      t[6] = (short)f2bf(u1.z); t[7] = (short)f2bf(u1.w);
      a[q] = t;
    }
  } else {
    const short8* Arow =
        (const short8*)((const unsigned short*)Aptr + (size_t)(r0 + (l & 15)) * 128 + ((l >> 4) << 3));
    #pragma unroll
    for (int q = 0; q < 4; ++q) a[q] = Arow[q * 4];
  }
  const short8* Wv = (const short8*)Wf + l;
  constexpr int NT = BNO / 16;
  float4v acc[NT];
  #pragma unroll
  for (int t = 0; t < NT; ++t) {
    acc[t] = (float4v){0.f, 0.f, 0.f, 0.f};
    #pragma unroll
    for (int q = 0; q < 4; ++q) {
      short8 b = Wv[(t * 4 + q) * 64];
      acc[t] = __builtin_amdgcn_mfma_f32_16x16x32_bf16(a[q], b, acc[t], 0, 0, 0);
    }
  }
  int orow = r0 + ((l >> 4) << 2);
  int ocol = l & 15;
  #pragma unroll
  for (int t = 0; t < NT; ++t) {
    #pragma unroll
    for (int r = 0; r < 4; ++r) {
      C[(size_t)(orow + r) * BNO + t * 16 + ocol] = f2bf(acc[t][r]);
    }
  }
}

// ---------------------------------------------------------------- aggregation (F=128)
// bf16 gather (8 rows in flight), fp32 accumulate, bf16 packed out + fused BN stats.
__global__ __launch_bounds__(256) void aggregate128_k(
    const unsigned short* __restrict__ Hb, const int* __restrict__ row_start,
    const int* __restrict__ deg, const int* __restrict__ csr_src,
    const float* __restrict__ csr_w, const float* __restrict__ dinv,
    const float* __restrict__ bias, unsigned int* __restrict__ outp,
    float* __restrict__ stats) {
  __shared__ float s_sum[128], s_sq[128];
  int tid = threadIdx.x;
  if (tid < 128) { s_sum[tid] = 0.f; s_sq[tid] = 0.f; }
  __syncthreads();
  int lane = tid & 63;
  int nwaves = gridDim.x * (blockDim.x >> 6);
  int gwave = (int)((blockIdx.x * blockDim.x + tid) >> 6);
  const unsigned int* Hu = (const unsigned int*)Hb;  // 64 uints/row (128 bf16)
  float bx = bias[2 * lane], by = bias[2 * lane + 1];
  float sx = 0.f, sy = 0.f, qx = 0.f, qy = 0.f;
  for (int node = gwave; node < kN; node += nwaves) {
    int rs = row_start[node];
    int dg = deg[node];
    float di = dinv[node];
    float ax = 0.f, ay = 0.f;
    int e = rs, end = rs + dg;
    for (; e + 8 <= end; e += 8) {
      int s[8];
      float w[8];
      unsigned int v[8];
      #pragma unroll
      for (int j = 0; j < 8; ++j) { s[j] = csr_src[e + j]; w[j] = csr_w[e + j]; }
      #pragma unroll
      for (int j = 0; j < 8; ++j) v[j] = Hu[(size_t)s[j] * 64 + lane];
      #pragma unroll
      for (int j = 0; j < 8; ++j) {
        ax += w[j] * bf2f(v[j] & 0xffffu);
        ay += w[j] * bf2f(v[j] >> 16);
      }
    }
    for (; e < end; ++e) {
      int s = csr_src[e];
      float w = csr_w[e];
      unsigned int v = Hu[(size_t)s * 64 + lane];
      ax += w * bf2f(v & 0xffffu);
      ay += w * bf2f(v >> 16);
    }
    unsigned int vs = Hu[(size_t)node * 64 + lane];
    float wse = di * di;
    float ox = ax + wse * bf2f(vs & 0xffffu) + bx;
    float oy = ay + wse * bf2f(vs >> 16) + by;
    outp[(size_t)node * 64 + lane] = pack2bf(ox, oy);
    sx += ox; sy += oy; qx += ox * ox; qy += oy * oy;
  }
  atomicAdd(&s_sum[2 * lane], sx);
  atomicAdd(&s_sum[2 * lane + 1], sy);
  atomicAdd(&s_sq[2 * lane], qx);
  atomicAdd(&s_sq[2 * lane + 1], qy);
  __syncthreads();
  if (tid < 128) {
    atomicAdd(&stats[tid], s_sum[tid]);
    atomicAdd(&stats[128 + tid], s_sq[tid]);
  }
}

// ---------------------------------------------------------------- aggregation (F=64, final)
// Half-wave per edge: 32 lanes x uint cover a 128B row; 2 edges/wave-step.
__global__ __launch_bounds__(256) void aggregate64_k(
    const unsigned short* __restrict__ Hb, const int* __restrict__ row_start,
    const int* __restrict__ deg, const int* __restrict__ csr_src,
    const float* __restrict__ csr_w, const float* __restrict__ dinv,
    const float* __restrict__ bias, float* __restrict__ outp) {
  int tid = threadIdx.x;
  int lane = tid & 63;
  int sub = lane >> 5;   // which edge of the pair
  int sl = lane & 31;    // column pair index
  int nwaves = gridDim.x * (blockDim.x >> 6);
  int gwave = (int)((blockIdx.x * blockDim.x + tid) >> 6);
  const unsigned int* Hu = (const unsigned int*)Hb;  // 32 uints/row (64 bf16)
  float bx = bias[2 * sl], by = bias[2 * sl + 1];
  for (int node = gwave; node < kN; node += nwaves) {
    int rs = row_start[node];
    int dg = deg[node];
    float di = dinv[node];
    float ax = 0.f, ay = 0.f;
    int e = rs, end = rs + dg;
    for (; e + 8 <= end; e += 8) {  // 8 edges: 4 per half-wave
      int s0 = csr_src[e + sub],     s1 = csr_src[e + 2 + sub];
      int s2 = csr_src[e + 4 + sub], s3 = csr_src[e + 6 + sub];
      float w0 = csr_w[e + sub],     w1 = csr_w[e + 2 + sub];
      float w2 = csr_w[e + 4 + sub], w3 = csr_w[e + 6 + sub];
      unsigned int v0 = Hu[(size_t)s0 * 32 + sl];
      unsigned int v1 = Hu[(size_t)s1 * 32 + sl];
      unsigned int v2 = Hu[(size_t)s2 * 32 + sl];
      unsigned int v3 = Hu[(size_t)s3 * 32 + sl];
      ax += w0 * bf2f(v0 & 0xffffu) + w1 * bf2f(v1 & 0xffffu) +
            w2 * bf2f(v2 & 0xffffu) + w3 * bf2f(v3 & 0xffffu);
      ay += w0 * bf2f(v0 >> 16) + w1 * bf2f(v1 >> 16) +
            w2 * bf2f(v2 >> 16) + w3 * bf2f(v3 >> 16);
    }
    for (; e + 2 <= end; e += 2) {
      int s = csr_src[e + sub];
      float w = csr_w[e + sub];
      unsigned int v = Hu[(size_t)s * 32 + sl];
      ax += w * bf2f(v & 0xffffu);
      ay += w * bf2f(v >> 16);
    }
    if (e < end) {  // odd remainder: half 0 does it, half 1 contributes 0
      int s = csr_src[e];
      float w = (sub == 0) ? csr_w[e] : 0.f;
      unsigned int v = Hu[(size_t)s * 32 + sl];
      ax += w * bf2f(v & 0xffffu);
      ay += w * bf2f(v >> 16);
    }
    ax += __shfl_xor(ax, 32, 64);
    ay += __shfl_xor(ay, 32, 64);
    unsigned int vs = Hu[(size_t)node * 32 + sl];
    float wse = di * di;
    float ox = ax + wse * bf2f(vs & 0xffffu) + bx;
    float oy = ay + wse * bf2f(vs >> 16) + by;
    if (sub == 0) ((float2*)outp)[(size_t)node * 32 + sl] = make_float2(ox, oy);
  }
}

// ---------------------------------------------------------------- BatchNorm
__global__ void bn_finalize_k(const float* __restrict__ stats, const float* __restrict__ g,
                              const float* __restrict__ be, float* __restrict__ ss) {
  int c = threadIdx.x;
  float mean = stats[c] * (1.f / kN);
  float var = stats[128 + c] * (1.f / kN) - mean * mean;
  float inv = rsqrtf(var + kEps);
  float sc = g[c] * inv;
  ss[c] = sc;
  ss[128 + c] = be[c] - mean * sc;
}

// z = scale[c]*a + shift[c] + r; optional bf16 z store; always bf16(relu(z)).
// a is packed bf16; residual is fp32 (layer1: x) or packed bf16 (layer2: z1).
template <bool WRITE_Z, bool RF32>
__global__ void bn_apply_res_k(const unsigned int* __restrict__ a, const void* __restrict__ rp,
                               const float* __restrict__ ss, unsigned int* __restrict__ z,
                               unsigned int* __restrict__ rb) {
  int idx = blockIdx.x * blockDim.x + threadIdx.x;  // kN*16 groups of 8 bf16
  if (idx >= kN * 16) return;
  uint4 av = ((const uint4*)a)[idx];
  float r[8];
  if constexpr (RF32) {
    float4 r0 = ((const float4*)rp)[idx * 2];
    float4 r1 = ((const float4*)rp)[idx * 2 + 1];
    r[0] = r0.x; r[1] = r0.y; r[2] = r0.z; r[3] = r0.w;
    r[4] = r1.x; r[5] = r1.y; r[6] = r1.z; r[7] = r1.w;
  } else {
    uint4 rv = ((const uint4*)rp)[idx];
    r[0] = bf2f(rv.x & 0xffffu); r[1] = bf2f(rv.x >> 16);
    r[2] = bf2f(rv.y & 0xffffu); r[3] = bf2f(rv.y >> 16);
    r[4] = bf2f(rv.z & 0xffffu); r[5] = bf2f(rv.z >> 16);
    r[6] = bf2f(rv.w & 0xffffu); r[7] = bf2f(rv.w >> 16);
  }
  int c = (idx & 15) * 8;
  float o[8];
  unsigned int apk[4] = {av.x, av.y, av.z, av.w};
  #pragma unroll
  for (int j = 0; j < 4; ++j) {
    o[2 * j]     = ss[c + 2 * j] * bf2f(apk[j] & 0xffffu) + ss[128 + c + 2 * j] + r[2 * j];
    o[2 * j + 1] = ss[c + 2 * j + 1] * bf2f(apk[j] >> 16) + ss[128 + c + 2 * j + 1] + r[2 * j + 1];
  }
  if (WRITE_Z) {
    uint4 zv;
    zv.x = pack2bf(o[0], o[1]); zv.y = pack2bf(o[2], o[3]);
    zv.z = pack2bf(o[4], o[5]); zv.w = pack2bf(o[6], o[7]);
    ((uint4*)z)[idx] = zv;
  }
  uint4 hv;
  hv.x = pack2bf(fmaxf(o[0], 0.f), fmaxf(o[1], 0.f));
  hv.y = pack2bf(fmaxf(o[2], 0.f), fmaxf(o[3], 0.f));
  hv.z = pack2bf(fmaxf(o[4], 0.f), fmaxf(o[5], 0.f));
  hv.w = pack2bf(fmaxf(o[6], 0.f), fmaxf(o[7], 0.f));
  ((uint4*)rb)[idx] = hv;
}

// ---------------------------------------------------------------- launch
extern "C" void kernel_launch(void* const* d_in, const int* in_sizes, int n_in,
                              void* d_out, int out_size, void* d_ws, size_t ws_size,
                              hipStream_t stream) {
  const float* x   = (const float*)d_in[0];
  const int*   ei  = (const int*)d_in[1];
  const float* W1  = (const float*)d_in[2];
  const float* b1  = (const float*)d_in[3];
  const float* g1  = (const float*)d_in[4];
  const float* be1 = (const float*)d_in[5];
  const float* W2  = (const float*)d_in[6];
  const float* b2  = (const float*)d_in[7];
  const float* g2  = (const float*)d_in[8];
  const float* be2 = (const float*)d_in[9];
  const float* W3  = (const float*)d_in[10];
  const float* b3  = (const float*)d_in[11];
  float* outp = (float*)d_out;

  const int* src = ei;
  const int* dst = ei + kE;

  char* ws = (char*)d_ws;
  size_t off = 0;
  auto alloc = [&](size_t bytes) -> void* {
    void* p = ws + off;
    off = (off + bytes + 255) & ~size_t(255);
    return p;
  };
  unsigned short* hH = (unsigned short*)alloc((size_t)kN * 128 * 2);  // gemm out (bf16)
  unsigned int* aB = (unsigned int*)alloc((size_t)kN * 64 * 4);       // agg out (packed bf16)
  unsigned int* zC = (unsigned int*)alloc((size_t)kN * 64 * 4);       // z1 residual (packed bf16)
  unsigned int* hb = (unsigned int*)alloc((size_t)kN * 64 * 4);       // relu out (packed bf16) / gemm in
  int*   csr_src  = (int*)alloc((size_t)kE * 4);
  float* csr_w    = (float*)alloc((size_t)kE * 4);
  float* dinv     = (float*)alloc((size_t)kN * 4);
  int*   deg      = (int*)alloc((size_t)kN * 4);
  int*   rowst    = (int*)alloc((size_t)kN * 4);
  int*   cursor   = (int*)alloc((size_t)kN * 4);
  float* stats    = (float*)alloc(256 * 4);
  float* ss       = (float*)alloc(256 * 4);
  int*   counter  = (int*)alloc(4);
  unsigned short* wf1 = (unsigned short*)alloc(128 * 128 * 2);
  unsigned short* wf2 = (unsigned short*)alloc(128 * 128 * 2);
  unsigned short* wf3 = (unsigned short*)alloc(128 * 64 * 2);

  const int TB = 256;
  int blkE = (kE + TB - 1) / TB;
  int blkNn = (kN + TB - 1) / TB;
  int blkGemm = (kN / 16 + 3) / 4;
  int blkApply = kN * 16 / TB;      // 6250
  const int blkAgg = 2048;

  // CSR build
  hipMemsetAsync(deg, 0, (size_t)kN * 4, stream);
  count_deg_k<<<blkE, TB, 0, stream>>>(dst, deg, counter);
  alloc_rows_k<<<blkNn, TB, 0, stream>>>(deg, rowst, cursor, counter, dinv);
  scatter_k<<<blkE, TB, 0, stream>>>(src, dst, dinv, cursor, csr_src, csr_w);
  convert_w_all_k<<<20, TB, 0, stream>>>(W1, W2, W3, wf1, wf2, wf3);

  // Layer 1 (A = fp32 x, residual = fp32 x)
  gemm_mfma_k<128, true><<<blkGemm, 256, 0, stream>>>(x, wf1, hH, stats);
  aggregate128_k<<<blkAgg, TB, 0, stream>>>(hH, rowst, deg, csr_src, csr_w, dinv, b1, aB, stats);
  bn_finalize_k<<<1, 128, 0, stream>>>(stats, g1, be1, ss);
  bn_apply_res_k<true, true><<<blkApply, TB, 0, stream>>>(aB, x, ss, zC, hb);

  // Layer 2 (residual = z1 bf16)
  gemm_mfma_k<128, false><<<blkGemm, 256, 0, stream>>>((const unsigned short*)hb, wf2, hH, stats);
  aggregate128_k<<<blkAgg, TB, 0, stream>>>(hH, rowst, deg, csr_src, csr_w, dinv, b2, aB, stats);
  bn_finalize_k<<<1, 128, 0, stream>>>(stats, g2, be2, ss);
  bn_apply_res_k<false, false><<<blkApply, TB, 0, stream>>>(aB, zC, ss, nullptr, hb);

  // Layer 3
  gemm_mfma_k<64, false><<<blkGemm, 256, 0, stream>>>((const unsigned short*)hb, wf3, hH, nullptr);
  aggregate64_k<<<blkAgg, TB, 0, stream>>>(hH, rowst, deg, csr_src, csr_w, dinv, b3, outp);
}